// Round 1
// baseline (1000.595 us; speedup 1.0000x reference)
//
#include <hip/hip_runtime.h>

#define HDIM  64
#define INDIM 7
#define QDIM  3
#define TDEC  288
#define SEQ   512
#define NB    4        // batches per block
#define CHUNK 32       // x timesteps staged per LDS chunk

__device__ __forceinline__ float sigm(float x) {
    // 1/(1+e^-x); inf-safe (exp->inf gives 0, exp->0 gives 1)
    return 1.0f / (1.0f + __expf(-x));
}
__device__ __forceinline__ float tanh_f(float x) {
    // clamp so exp never produces inf (inf/inf = NaN)
    float xx = fminf(fmaxf(x, -15.0f), 15.0f);
    float e = __expf(2.0f * xx);
    return (e - 1.0f) / (e + 1.0f);
}

// One block = NB batch elements, full encoder (512 steps) + decoder (288 steps).
// Encoder GEMM phase: thread (wave=gate g, lane=unit j) owns W_hh row g*64+j in
// registers (static-indexed float4[16]); h read from LDS via same-address
// broadcast (conflict-free). Activation phase: thread -> (batch=wave, unit=lane),
// cell state c lives in a register for the whole kernel.
__global__ __launch_bounds__(256, 2)
void enc_dec_kernel(const float* __restrict__ x,
                    const float* __restrict__ eWih, const float* __restrict__ eWhh,
                    const float* __restrict__ ebih, const float* __restrict__ ebhh,
                    const float* __restrict__ dWih, const float* __restrict__ dWhh,
                    const float* __restrict__ dbih, const float* __restrict__ dbhh,
                    const float* __restrict__ oW,   const float* __restrict__ obv,
                    float* __restrict__ out)
{
    __shared__ float lds_h[NB][HDIM];
    __shared__ float lds_g[NB][4 * HDIM];
    __shared__ float lds_x[2][NB][CHUNK][8];   // padded 7->8, pad lane zeroed

    const int tid  = threadIdx.x;
    const int lane = tid & 63;
    const int wid  = tid >> 6;
    const int b0   = blockIdx.x * NB;

    const int row = wid * HDIM + lane;   // gate-matrix row this thread owns

    // ---- encoder weights into registers (fully static indexing) ----
    float4 whh[16];
#pragma unroll
    for (int m4 = 0; m4 < 16; ++m4)
        whh[m4] = *reinterpret_cast<const float4*>(&eWhh[row * HDIM + m4 * 4]);
    float wih[8];
#pragma unroll
    for (int k = 0; k < 7; ++k) wih[k] = eWih[row * INDIM + k];
    wih[7] = 0.0f;
    const float bias = ebih[row] + ebhh[row];

    // ---- init state ----
    lds_h[wid][lane] = 0.0f;   // 256 threads cover NB*HDIM exactly
    float c_reg = 0.0f;        // c for (batch=wid, unit=lane)

    // ---- load x chunk 0 ----
    for (int i = tid; i < NB * CHUNK * 8; i += 256) {
        int b = i >> 8;          // CHUNK*8 == 256
        int r = i & 255;
        int s = r >> 3;
        int k = r & 7;
        float v = 0.0f;
        if (k < 7) v = x[((size_t)(b0 + b) * SEQ + s) * INDIM + k];
        lds_x[0][b][s][k] = v;
    }
    __syncthreads();

    // ================= encoder: 512 serial steps =================
    for (int s = 0; s < SEQ; ++s) {
        const int cs  = s & (CHUNK - 1);
        const int buf = (s >> 5) & 1;

        // ---- GEMM phase: gates[b][row] for NB batches ----
        float acc[NB];
#pragma unroll
        for (int b = 0; b < NB; ++b) acc[b] = bias;

#pragma unroll
        for (int b = 0; b < NB; ++b) {
            const float4 xlo = *reinterpret_cast<const float4*>(&lds_x[buf][b][cs][0]);
            const float4 xhi = *reinterpret_cast<const float4*>(&lds_x[buf][b][cs][4]);
            acc[b] += xlo.x * wih[0] + xlo.y * wih[1] + xlo.z * wih[2] + xlo.w * wih[3]
                    + xhi.x * wih[4] + xhi.y * wih[5] + xhi.z * wih[6];
        }
#pragma unroll
        for (int m4 = 0; m4 < 16; ++m4) {
            const float4 w = whh[m4];
#pragma unroll
            for (int b = 0; b < NB; ++b) {
                const float4 hv = *reinterpret_cast<const float4*>(&lds_h[b][m4 * 4]);
                acc[b] = fmaf(hv.x, w.x, acc[b]);
                acc[b] = fmaf(hv.y, w.y, acc[b]);
                acc[b] = fmaf(hv.z, w.z, acc[b]);
                acc[b] = fmaf(hv.w, w.w, acc[b]);
            }
        }
#pragma unroll
        for (int b = 0; b < NB; ++b) lds_g[b][row] = acc[b];
        __syncthreads();

        // ---- activation phase: thread -> (batch=wid, unit=lane) ----
        {
            const int b = wid, j = lane;
            float ig = sigm(lds_g[b][j]);
            float fg = sigm(lds_g[b][HDIM + j]);
            float gg = tanh_f(lds_g[b][2 * HDIM + j]);
            float og = sigm(lds_g[b][3 * HDIM + j]);
            c_reg = fg * c_reg + ig * gg;
            lds_h[b][j] = og * tanh_f(c_reg);
        }

        // ---- prefetch next x chunk (a full chunk of slack to hide HBM) ----
        if (cs == 0 && s + CHUNK < SEQ) {
            const int nbuf = buf ^ 1;
            const int s0n  = s + CHUNK;
            for (int i = tid; i < NB * CHUNK * 8; i += 256) {
                int b = i >> 8;
                int r = i & 255;
                int ss = r >> 3;
                int k = r & 7;
                float v = 0.0f;
                if (k < 7) v = x[((size_t)(b0 + b) * SEQ + (s0n + ss)) * INDIM + k];
                lds_x[nbuf][b][ss][k] = v;
            }
        }
        __syncthreads();
    }
    // lds_h = h_enc; c_reg (thread (wid,lane)) = c_enc[b][j]

    // ====== decoder gbase = b + h_enc @ dW_hh.T  (constant over all T steps) ======
    {
        float4 dwhh[16];
#pragma unroll
        for (int m4 = 0; m4 < 16; ++m4)
            dwhh[m4] = *reinterpret_cast<const float4*>(&dWhh[row * HDIM + m4 * 4]);
        const float dbias = dbih[row] + dbhh[row];

        float acc[NB];
#pragma unroll
        for (int b = 0; b < NB; ++b) acc[b] = dbias;
#pragma unroll
        for (int m4 = 0; m4 < 16; ++m4) {
            const float4 w = dwhh[m4];
#pragma unroll
            for (int b = 0; b < NB; ++b) {
                const float4 hv = *reinterpret_cast<const float4*>(&lds_h[b][m4 * 4]);
                acc[b] = fmaf(hv.x, w.x, acc[b]);
                acc[b] = fmaf(hv.y, w.y, acc[b]);
                acc[b] = fmaf(hv.z, w.z, acc[b]);
                acc[b] = fmaf(hv.w, w.w, acc[b]);
            }
        }
#pragma unroll
        for (int b = 0; b < NB; ++b) lds_g[b][row] = acc[b];
    }
    __syncthreads();

    // ================= decoder: wave = one batch, lane = unit =================
    {
        const int b = wid, j = lane;
        const float c_e = c_reg;
        const float gb0 = lds_g[b][j];
        const float gb1 = lds_g[b][HDIM + j];
        const float gb2 = lds_g[b][2 * HDIM + j];
        const float gb3 = lds_g[b][3 * HDIM + j];

        const float w00 = dWih[(0 * HDIM + j) * QDIM + 0], w01 = dWih[(0 * HDIM + j) * QDIM + 1], w02 = dWih[(0 * HDIM + j) * QDIM + 2];
        const float w10 = dWih[(1 * HDIM + j) * QDIM + 0], w11 = dWih[(1 * HDIM + j) * QDIM + 1], w12 = dWih[(1 * HDIM + j) * QDIM + 2];
        const float w20 = dWih[(2 * HDIM + j) * QDIM + 0], w21 = dWih[(2 * HDIM + j) * QDIM + 1], w22 = dWih[(2 * HDIM + j) * QDIM + 2];
        const float w30 = dWih[(3 * HDIM + j) * QDIM + 0], w31 = dWih[(3 * HDIM + j) * QDIM + 1], w32 = dWih[(3 * HDIM + j) * QDIM + 2];
        const float ow0 = oW[0 * HDIM + j], ow1 = oW[1 * HDIM + j], ow2 = oW[2 * HDIM + j];
        const float ob0 = obv[0], ob1 = obv[1], ob2 = obv[2];

        float y0 = 0.0f, y1 = 0.0f, y2 = 0.0f;
        float* outp = out + (size_t)(b0 + b) * TDEC * QDIM;

        for (int t = 0; t < TDEC; ++t) {
            float g0 = gb0 + y0 * w00 + y1 * w01 + y2 * w02;
            float g1 = gb1 + y0 * w10 + y1 * w11 + y2 * w12;
            float g2 = gb2 + y0 * w20 + y1 * w21 + y2 * w22;
            float g3 = gb3 + y0 * w30 + y1 * w31 + y2 * w32;
            float ig = sigm(g0), fg = sigm(g1), gg = tanh_f(g2), og = sigm(g3);
            float c = fg * c_e + ig * gg;
            float h = og * tanh_f(c);
            float r0 = h * ow0, r1 = h * ow1, r2 = h * ow2;
#pragma unroll
            for (int d = 1; d < 64; d <<= 1) {
                r0 += __shfl_xor(r0, d);
                r1 += __shfl_xor(r1, d);
                r2 += __shfl_xor(r2, d);
            }
            y0 = r0 + ob0;
            y1 = r1 + ob1;
            y2 = r2 + ob2;
            if (j < QDIM) outp[t * QDIM + j] = (j == 0) ? y0 : (j == 1) ? y1 : y2;
        }
    }
}

extern "C" void kernel_launch(void* const* d_in, const int* in_sizes, int n_in,
                              void* d_out, int out_size, void* d_ws, size_t ws_size,
                              hipStream_t stream) {
    (void)in_sizes; (void)n_in; (void)d_ws; (void)ws_size; (void)out_size;
    const float* x    = (const float*)d_in[0];
    const float* eWih = (const float*)d_in[1];
    const float* eWhh = (const float*)d_in[2];
    const float* ebih = (const float*)d_in[3];
    const float* ebhh = (const float*)d_in[4];
    const float* dWih = (const float*)d_in[5];
    const float* dWhh = (const float*)d_in[6];
    const float* dbih = (const float*)d_in[7];
    const float* dbhh = (const float*)d_in[8];
    const float* oW   = (const float*)d_in[9];
    const float* obv  = (const float*)d_in[10];
    float* out = (float*)d_out;

    const int B = 2048;
    dim3 grid(B / NB), block(256);
    enc_dec_kernel<<<grid, block, 0, stream>>>(x, eWih, eWhh, ebih, ebhh,
                                               dWih, dWhh, dbih, dbhh, oW, obv, out);
}